// Round 8
// baseline (342.385 us; speedup 1.0000x reference)
//
#include <hip/hip_runtime.h>
#include <math.h>

#define N_NODES 100000
#define N_EDGES 100000
#define NNZT    1600000
#define C       128
#define NB      ((N_NODES + 255) >> 8)    // 391 node-buckets of 256 nodes
#define CHUNK   4096                      // edges per k_part block
#define SCAP    5120                      // k_bsort slab capacity (mean 4092, sigma~64)
#define NTILES  (N_NODES / 16)            // 6250 16-row output tiles

typedef _Float16 half8 __attribute__((ext_vector_type(8)));
typedef _Float16 h2    __attribute__((ext_vector_type(2)));
typedef float    f32x4 __attribute__((ext_vector_type(4)));

// K1: t_node[i] = dot(x_0[i], a_tgt); also emit x0h = (fp16)x0.
__global__ __launch_bounds__(256) void k1_node_dot(
    const float* __restrict__ x0, const float* __restrict__ att,
    float* __restrict__ t_node, _Float16* __restrict__ x0h)
{
    int wave = threadIdx.x >> 6;
    int lane = threadIdx.x & 63;
    int node = blockIdx.x * 4 + wave;          // 100000 % 4 == 0
    const float2 xv = *reinterpret_cast<const float2*>(x0 + (size_t)node * C + lane * 2);
    h2 hx = { (_Float16)xv.x, (_Float16)xv.y };
    *reinterpret_cast<h2*>(x0h + (size_t)node * C + lane * 2) = hx;
    const float2 av = *reinterpret_cast<const float2*>(att + C + lane * 2);
    float v = xv.x * av.x + xv.y * av.y;
    #pragma unroll
    for (int off = 32; off > 0; off >>= 1) v += __shfl_xor(v, off, 64);
    if (lane == 0) t_node[node] = v;
}

// RP: edge row pointer from sorted edge_idx, atomic-free one pass.
__global__ __launch_bounds__(256) void k_rowptr(
    const int* __restrict__ edge_idx, int* __restrict__ row_start)
{
    int e = blockIdx.x * 256 + threadIdx.x;
    if (e >= NNZT) return;
    int j = edge_idx[e];
    int jprev = (e == 0) ? -1 : edge_idx[e - 1];
    for (int k = jprev + 1; k <= j; ++k) row_start[k] = e;
    if (e == NNZT - 1)
        for (int k = j + 1; k <= N_EDGES; ++k) row_start[k] = NNZT;
}

// WC: Wt[n][k] = (fp16) W[k][n]  (transposed fp16 weight for MFMA B-frags)
__global__ __launch_bounds__(256) void k_wcvt(
    const float* __restrict__ W, _Float16* __restrict__ wt)
{
    int i = blockIdx.x * 256 + threadIdx.x;   // 16384
    int k = i >> 7, n = i & 127;
    wt[(size_t)n * C + k] = (_Float16)W[(size_t)k * C + n];
}

// K2: segment sum -> m01h row (fp16) + s_edge dot, via row_start.
// ONE WAVE PER ROW: 4 edge-slots x 16 lanes x half8, 4-wide MLP unroll.
// No NT hints (round-2: NT on shared streams poisons later kernels' L2 reuse).
__global__ __launch_bounds__(256) void k2_edge_msg(
    const half8* __restrict__ x0h,
    const int*   __restrict__ node_idx,
    const int*   __restrict__ row_start,
    const float* __restrict__ values,
    const float* __restrict__ att,
    _Float16* __restrict__ m01h,
    float* __restrict__ s_edge)
{
    int wave = threadIdx.x >> 6;
    int lane = threadIdx.x & 63;
    int j    = blockIdx.x * 4 + wave;          // 100000 % 4 == 0
    int sub  = lane >> 4;                      // 0..3 edge slot
    int ln   = lane & 15;                      // half8 chunk of the row
    int start = row_start[j];
    int end   = row_start[j + 1];

    h2 hacc[4];
    #pragma unroll
    for (int q = 0; q < 4; ++q) hacc[q] = (h2){(_Float16)0.f, (_Float16)0.f};

    int e = start + sub;
    for (; e + 12 < end; e += 16) {
        int n0 = node_idx[e];
        int n1 = node_idx[e + 4];
        int n2 = node_idx[e + 8];
        int n3 = node_idx[e + 12];
        float f0 = values[e];
        float f1 = values[e + 4];
        float f2 = values[e + 8];
        float f3 = values[e + 12];
        half8 A  = x0h[(size_t)n0 * 16 + ln];
        half8 B  = x0h[(size_t)n1 * 16 + ln];
        half8 Cg = x0h[(size_t)n2 * 16 + ln];
        half8 D  = x0h[(size_t)n3 * 16 + ln];
        _Float16 v0 = (_Float16)f0, v1 = (_Float16)f1;
        _Float16 v2 = (_Float16)f2, v3 = (_Float16)f3;
        h2 v0p = {v0, v0}, v1p = {v1, v1}, v2p = {v2, v2}, v3p = {v3, v3};
        const h2* a2 = reinterpret_cast<const h2*>(&A);
        const h2* b2 = reinterpret_cast<const h2*>(&B);
        const h2* c2 = reinterpret_cast<const h2*>(&Cg);
        const h2* d2 = reinterpret_cast<const h2*>(&D);
        #pragma unroll
        for (int q = 0; q < 4; ++q)
            hacc[q] = a2[q] * v0p
                    + (b2[q] * v1p + (c2[q] * v2p + (d2[q] * v3p + hacc[q])));
    }
    for (; e + 4 < end; e += 8) {
        int n0 = node_idx[e];
        int n1 = node_idx[e + 4];
        _Float16 v0 = (_Float16)values[e];
        _Float16 v1 = (_Float16)values[e + 4];
        h2 v0p = {v0, v0}, v1p = {v1, v1};
        half8 A = x0h[(size_t)n0 * 16 + ln];
        half8 B = x0h[(size_t)n1 * 16 + ln];
        const h2* a2 = reinterpret_cast<const h2*>(&A);
        const h2* b2 = reinterpret_cast<const h2*>(&B);
        #pragma unroll
        for (int q = 0; q < 4; ++q)
            hacc[q] = a2[q] * v0p + (b2[q] * v1p + hacc[q]);
    }
    if (e < end) {
        int n0 = node_idx[e];
        _Float16 v0 = (_Float16)values[e];
        h2 v0p = {v0, v0};
        half8 A = x0h[(size_t)n0 * 16 + ln];
        const h2* a2 = reinterpret_cast<const h2*>(&A);
        #pragma unroll
        for (int q = 0; q < 4; ++q) hacc[q] = a2[q] * v0p + hacc[q];
    }

    float f[8];
    #pragma unroll
    for (int q = 0; q < 4; ++q) {
        f[2 * q]     = (float)hacc[q][0];
        f[2 * q + 1] = (float)hacc[q][1];
    }
    #pragma unroll
    for (int q = 0; q < 8; ++q) {
        f[q] += __shfl_xor(f[q], 16, 64);
        f[q] += __shfl_xor(f[q], 32, 64);
    }
    if (lane < 16) {
        half8 hv;
        #pragma unroll
        for (int q = 0; q < 8; ++q) hv[q] = (_Float16)f[q];
        reinterpret_cast<half8*>(m01h + (size_t)j * C)[ln] = hv;
    }
    f32x4 a0 = *reinterpret_cast<const f32x4*>(att + ln * 8);
    f32x4 a1 = *reinterpret_cast<const f32x4*>(att + ln * 8 + 4);
    float p = f[0] * a0[0] + f[1] * a0[1] + f[2] * a0[2] + f[3] * a0[3]
            + f[4] * a1[0] + f[5] * a1[1] + f[6] * a1[2] + f[7] * a1[3];
    #pragma unroll
    for (int off = 8; off > 0; off >>= 1) p += __shfl_xor(p, off, 64);
    if (lane == 0) s_edge[j] = p;
}

// BH: per-bucket totals. Wave-private LDS histograms -> ~100k global adds.
__global__ __launch_bounds__(256) void k_bhist(
    const int* __restrict__ node_idx, int* __restrict__ btot)
{
    __shared__ int cnt4[4][NB];
    int tid = threadIdx.x;
    int w   = tid >> 6;
    for (int b = tid; b < 4 * NB; b += 256) (&cnt4[0][0])[b] = 0;
    __syncthreads();
    const int per = (NNZT + 255) / 256;   // 6250
    int e0 = blockIdx.x * per;
    int e1 = e0 + per; if (e1 > NNZT) e1 = NNZT;
    for (int e = e0 + tid; e < e1; e += 256)
        atomicAdd(&cnt4[w][node_idx[e] >> 8], 1);
    __syncthreads();
    for (int b = tid; b < NB; b += 256) {
        int cc = cnt4[0][b] + cnt4[1][b] + cnt4[2][b] + cnt4[3][b];
        if (cc) atomicAdd(&btot[b], cc);
    }
}

// BS: exclusive scan of 391 bucket totals -> bbase[0..NB], bcur init.
__global__ __launch_bounds__(512) void k_bscan(
    const int* __restrict__ btot, int* __restrict__ bbase, int* __restrict__ bcur)
{
    __shared__ int s[512];
    int tid = threadIdx.x;
    int v = (tid < NB) ? btot[tid] : 0;
    s[tid] = v;
    __syncthreads();
    for (int off = 1; off < 512; off <<= 1) {
        int t = (tid >= off) ? s[tid - off] : 0;
        __syncthreads();
        s[tid] += t;
        __syncthreads();
    }
    if (tid < NB) { bbase[tid] = s[tid] - v; bcur[tid] = s[tid] - v; }
    if (tid == NB - 1) bbase[NB] = s[tid];
}

// PART: LDS counting-sort partition (temporal-density writes; verified
// round 4: write amplification ~1x). Record: {(n&255)<<17 | j, coef}.
__global__ __launch_bounds__(512) void k_part(
    const int*   __restrict__ node_idx,
    const int*   __restrict__ edge_idx,
    const float* __restrict__ values,
    const float* __restrict__ s_edge,
    const float* __restrict__ t_node,
    int*  __restrict__ bcur,
    int2* __restrict__ rec)
{
    __shared__ int hist[NB];
    __shared__ int lbase[NB];
    __shared__ int gb[NB];
    __shared__ int cur[NB];
    __shared__ int2 lrec[CHUNK];                  // 32 KB
    __shared__ unsigned short lbid[CHUNK];        // 8 KB
    int tid = threadIdx.x;
    int e0 = blockIdx.x * CHUNK;
    int m = NNZT - e0; if (m > CHUNK) m = CHUNK;

    for (int b = tid; b < NB; b += 512) hist[b] = 0;
    __syncthreads();
    for (int i = tid; i < m; i += 512)
        atomicAdd(&hist[node_idx[e0 + i] >> 8], 1);
    __syncthreads();
    int c = (tid < NB) ? hist[tid] : 0;
    for (int off = 1; off < NB; off <<= 1) {
        int t = 0;
        if (tid < NB && tid >= off) t = hist[tid - off];
        __syncthreads();
        if (tid < NB) hist[tid] += t;
        __syncthreads();
    }
    if (tid < NB) {
        int excl = hist[tid] - c;
        lbase[tid] = excl;
        cur[tid]   = excl;
        gb[tid]    = c ? atomicAdd(&bcur[tid], c) : 0;
    }
    __syncthreads();
    for (int i = tid; i < m; i += 512) {
        int e = e0 + i;
        int n = node_idx[e];
        int b = n >> 8;
        int j = edge_idx[e];
        float v = values[e];
        float s = s_edge[j] + t_node[n];
        float coef = (s > 0.f ? s : expm1f(s)) * v;
        int slot = atomicAdd(&cur[b], 1);
        lrec[slot] = make_int2(((n & 255) << 17) | j, __float_as_int(coef));
        lbid[slot] = (unsigned short)b;
    }
    __syncthreads();
    for (int s = tid; s < m; s += 512) {
        int b = lbid[s];
        rec[gb[b] + (s - lbase[b])] = lrec[s];
    }
}

// BSORT: one block per bucket. ONE sequential read of the slab into LDS,
// node-sort via 256-counter hist+scan+ord, ONE dense sequential write of the
// sorted slab (jc) + per-node base/count.
__global__ __launch_bounds__(512) void k_bsort(
    const int2* __restrict__ rec,
    const int*  __restrict__ bbase,
    int2* __restrict__ jc,
    int*  __restrict__ base,
    int*  __restrict__ count)
{
    __shared__ int cnt[256], bl[256], cur[256];
    __shared__ int2 lrec[SCAP];                // 40 KB
    __shared__ unsigned short ord[SCAP];       // 10 KB
    int b = blockIdx.x, tid = threadIdx.x;
    int lo = bbase[b], hi = bbase[b + 1];
    int m = hi - lo;
    bool ovf = (m > SCAP);   // never for this data (mean 4092, cap = +16 sigma)

    if (tid < 256) cnt[tid] = 0;
    __syncthreads();
    for (int i = tid; i < m; i += 512) {
        int2 r = rec[lo + i];
        if (i < SCAP) lrec[i] = r;
        atomicAdd(&cnt[((unsigned)r.x) >> 17], 1);
    }
    __syncthreads();
    if (tid < 256) bl[tid] = cnt[tid];
    __syncthreads();
    for (int off = 1; off < 256; off <<= 1) {
        int t = 0;
        if (tid < 256 && tid >= off) t = bl[tid - off];
        __syncthreads();
        if (tid < 256) bl[tid] += t;
        __syncthreads();
    }
    if (tid < 256) {
        int excl = bl[tid] - cnt[tid];
        cur[tid] = excl;
        int nn = (b << 8) + tid;
        if (nn < N_NODES) { base[nn] = lo + excl; count[nn] = cnt[tid]; }
    }
    __syncthreads();
    if (!ovf) {
        for (int i = tid; i < m; i += 512) {
            int local = ((unsigned)lrec[i].x) >> 17;
            int p = atomicAdd(&cur[local], 1);
            ord[p] = (unsigned short)i;
        }
        __syncthreads();
        for (int s = tid; s < m; s += 512)
            jc[lo + s] = lrec[ord[s]];
    } else {
        // correct-but-slow fallback: scattered (within-slab) direct writes
        for (int i = tid; i < m; i += 512) {
            int2 r = rec[lo + i];
            int local = ((unsigned)r.x) >> 17;
            int p = atomicAdd(&cur[local], 1);
            jc[lo + p] = r;
        }
    }
}

// K3M: fused gather + output GEMM, BARRIER-FREE. One WAVE owns one 16-row
// output tile: gathers its 16 nodes back-to-back (long uninterrupted load
// pipeline, 6% relative imbalance vs 18% at 2 nodes), writes rows into a
// wave-PRIVATE LDS tile, then does its own 16x128 @ 128x128 MFMA (verified
// k4 layout). Zero __syncthreads -> no convoy, no pipeline drain; waves are
// fully independent like k2 (which delivers ~3+ TB/s on this access pattern).
__global__ __launch_bounds__(256) void k3m(
    const int2*  __restrict__ jc,
    const int*   __restrict__ base,
    const int*   __restrict__ count,
    const half8* __restrict__ m01h,
    const _Float16* __restrict__ wt,   // wt[n*C+k] = W[k][n]
    float* __restrict__ out)
{
    __shared__ _Float16 yt[4][16][136];  // 17408B; wave-private [wave] slices
    int tid  = threadIdx.x;
    int wave = tid >> 6, lane = tid & 63, sub = lane >> 4, ln = lane & 15;
    int t = blockIdx.x * 4 + wave;       // tile index
    if (t >= NTILES) return;             // safe: no barriers in this kernel
    int nb = t * 16;

    for (int row = 0; row < 16; ++row) {
        int n  = nb + row;
        int b  = base[n];
        int cc = count[n];
        float facc[8];
        #pragma unroll
        for (int q = 0; q < 8; ++q) facc[q] = 0.f;
        int i = sub;
        for (; i + 12 < cc; i += 16) {            // 4-wide MLP
            int2 r0 = jc[b + i];
            int2 r1 = jc[b + i + 4];
            int2 r2 = jc[b + i + 8];
            int2 r3 = jc[b + i + 12];
            half8 a0 = m01h[(size_t)(r0.x & 0x1FFFF) * 16 + ln];
            half8 a1 = m01h[(size_t)(r1.x & 0x1FFFF) * 16 + ln];
            half8 a2 = m01h[(size_t)(r2.x & 0x1FFFF) * 16 + ln];
            half8 a3 = m01h[(size_t)(r3.x & 0x1FFFF) * 16 + ln];
            float c0 = __int_as_float(r0.y);
            float c1 = __int_as_float(r1.y);
            float c2 = __int_as_float(r2.y);
            float c3 = __int_as_float(r3.y);
            #pragma unroll
            for (int q = 0; q < 8; ++q)
                facc[q] += c0 * (float)a0[q] + c1 * (float)a1[q]
                         + c2 * (float)a2[q] + c3 * (float)a3[q];
        }
        for (; i + 4 < cc; i += 8) {              // 2-wide tail
            int2 r0 = jc[b + i];
            int2 r1 = jc[b + i + 4];
            half8 a0 = m01h[(size_t)(r0.x & 0x1FFFF) * 16 + ln];
            half8 a1 = m01h[(size_t)(r1.x & 0x1FFFF) * 16 + ln];
            float c0 = __int_as_float(r0.y);
            float c1 = __int_as_float(r1.y);
            #pragma unroll
            for (int q = 0; q < 8; ++q)
                facc[q] += c0 * (float)a0[q] + c1 * (float)a1[q];
        }
        if (i < cc) {                             // 1-wide tail
            int2 r0 = jc[b + i];
            half8 a0 = m01h[(size_t)(r0.x & 0x1FFFF) * 16 + ln];
            float c0 = __int_as_float(r0.y);
            #pragma unroll
            for (int q = 0; q < 8; ++q) facc[q] += c0 * (float)a0[q];
        }
        #pragma unroll
        for (int q = 0; q < 8; ++q) {
            facc[q] += __shfl_xor(facc[q], 16, 64);
            facc[q] += __shfl_xor(facc[q], 32, 64);
        }
        if (lane < 16) {
            half8 hv;
            #pragma unroll
            for (int q = 0; q < 8; ++q) hv[q] = (_Float16)facc[q];
            *reinterpret_cast<half8*>(&yt[wave][row][ln * 8]) = hv;
        }
    }
    // same-wave LDS write->read: program order + compiler lgkmcnt, no barrier.

    // MFMA epilogue: this wave's 16x128 tile @ W, 8 col-tiles x 4 k-chunks.
    int m    = lane & 15;
    int quad = lane >> 4;
    half8 a[4];
    #pragma unroll
    for (int kc = 0; kc < 4; ++kc)
        a[kc] = *reinterpret_cast<const half8*>(&yt[wave][m][quad * 8 + kc * 32]);
    #pragma unroll
    for (int ct = 0; ct < 8; ++ct) {
        const _Float16* wrow = wt + (size_t)(ct * 16 + m) * C + quad * 8;
        f32x4 acc = {0.f, 0.f, 0.f, 0.f};
        #pragma unroll
        for (int kc = 0; kc < 4; ++kc) {
            half8 bfr = *reinterpret_cast<const half8*>(wrow + kc * 32);
            acc = __builtin_amdgcn_mfma_f32_16x16x32_f16(a[kc], bfr, acc, 0, 0, 0);
        }
        int orow = nb + quad * 4;
        int ocol = ct * 16 + m;
        #pragma unroll
        for (int r = 0; r < 4; ++r)
            out[(size_t)(orow + r) * C + ocol] = acc[r];
    }
}

extern "C" void kernel_launch(void* const* d_in, const int* in_sizes, int n_in,
                              void* d_out, int out_size, void* d_ws, size_t ws_size,
                              hipStream_t stream)
{
    const float* x0       = (const float*)d_in[0];
    const int*   node_idx = (const int*)  d_in[1];
    const int*   edge_idx = (const int*)  d_in[2];
    const float* values   = (const float*)d_in[3];
    const float* W        = (const float*)d_in[4];
    const float* att      = (const float*)d_in[5];
    float* out = (float*)d_out;

    // d_out: [x0h 25.6MB][spare]. x0h dead after k2 -> rec (12.8MB) overlays it;
    // rec dead after k_bsort. k3m writes out (51.2MB = all of d_out) last.
    // m01h lives in ws (must stay live while k3m writes out).
    _Float16* x0h_s = (_Float16*)d_out;
    int2* rec = (int2*)d_out;                                  // 12.8 MB over x0h

    char*  p   = (char*)d_ws;
    _Float16* m01h_s = (_Float16*)p; p += (size_t)N_EDGES * C * sizeof(_Float16); // 25.6 MB
    int2*  jc       = (int2*)p;   p += (size_t)NNZT * sizeof(int2);               // 12.8 MB
    float* t_node   = (float*)p;  p += N_NODES * sizeof(float);
    float* s_edge   = (float*)p;  p += N_EDGES * sizeof(float);
    int*   base     = (int*)p;    p += N_NODES * sizeof(int);
    int*   count    = (int*)p;    p += N_NODES * sizeof(int);
    int*   btot     = (int*)p;    p += 512 * sizeof(int);
    int*   bbase    = (int*)p;    p += 512 * sizeof(int);
    int*   bcur     = (int*)p;    p += 512 * sizeof(int);
    int*   row_start= (int*)p;    p += (N_EDGES + 1) * sizeof(int);
    _Float16* wt    = (_Float16*)p; p += (size_t)C * C * sizeof(_Float16);        // 32 KB

    hipMemsetAsync(btot, 0, NB * sizeof(int), stream);

    k1_node_dot<<<N_NODES / 4, 256, 0, stream>>>(x0, att, t_node, x0h_s);
    k_rowptr<<<(NNZT + 255) / 256, 256, 0, stream>>>(edge_idx, row_start);
    k_wcvt  <<<(C * C + 255) / 256, 256, 0, stream>>>(W, wt);
    k2_edge_msg<<<N_EDGES / 4, 256, 0, stream>>>((const half8*)x0h_s, node_idx, row_start,
                                                 values, att, m01h_s, s_edge);

    k_bhist<<<256, 256, 0, stream>>>(node_idx, btot);
    k_bscan<<<1, 512, 0, stream>>>(btot, bbase, bcur);
    k_part <<<(NNZT + CHUNK - 1) / CHUNK, 512, 0, stream>>>(node_idx, edge_idx, values,
                                                            s_edge, t_node, bcur, rec);
    k_bsort<<<NB, 512, 0, stream>>>(rec, bbase, jc, base, count);
    k3m    <<<(NTILES + 3) / 4, 256, 0, stream>>>(jc, base, count, (const half8*)m01h_s,
                                                  wt, out);
}

// Round 9
// 318.344 us; speedup vs baseline: 1.0755x; 1.0755x over previous
//
#include <hip/hip_runtime.h>
#include <math.h>

#define N_NODES 100000
#define N_EDGES 100000
#define NNZT    1600000
#define C       128
#define NB      ((N_NODES + 255) >> 8)    // 391 node-buckets of 256 nodes
#define CHUNK   4096                      // edges per k_part block
#define SCAP    5120                      // k_bsort slab capacity (mean 4092, sigma~64)

// prep kernel block-range split
#define K1B (N_NODES / 4)                 // 25000 blocks: k1 body
#define RPB ((NNZT + 255) / 256)          // 6250 blocks: rowptr body
#define WCB (C * C / 256)                 // 64 blocks: wcvt body
#define BHB 256                           // 256 blocks: bhist body

typedef _Float16 half8 __attribute__((ext_vector_type(8)));
typedef _Float16 h2    __attribute__((ext_vector_type(2)));
typedef float    f32x4 __attribute__((ext_vector_type(4)));

// PREP: fusion of 4 mutually-independent kernels (k1 node-dot + x0h cast,
// rowptr, weight transpose+cast, bucket histogram) via block-range split.
// Saves 3 dependency-drained dispatch gaps (~8us each). Branch is
// block-uniform; LDS (bhist's 6.25KB) is small enough not to cap occupancy.
__global__ __launch_bounds__(256) void k_prep(
    const float* __restrict__ x0, const float* __restrict__ att,
    const int*   __restrict__ node_idx, const int* __restrict__ edge_idx,
    const float* __restrict__ W,
    float* __restrict__ t_node, _Float16* __restrict__ x0h,
    int* __restrict__ row_start, _Float16* __restrict__ wt,
    int* __restrict__ btot)
{
    __shared__ int cnt4[4][NB];
    int bid = blockIdx.x;
    int tid = threadIdx.x;

    if (bid < K1B) {
        // ---- k1: t_node + x0h cast (one wave per node row) ----
        int wave = tid >> 6;
        int lane = tid & 63;
        int node = bid * 4 + wave;                 // 100000 % 4 == 0
        const float2 xv = *reinterpret_cast<const float2*>(x0 + (size_t)node * C + lane * 2);
        h2 hx = { (_Float16)xv.x, (_Float16)xv.y };
        *reinterpret_cast<h2*>(x0h + (size_t)node * C + lane * 2) = hx;
        const float2 av = *reinterpret_cast<const float2*>(att + C + lane * 2);
        float v = xv.x * av.x + xv.y * av.y;
        #pragma unroll
        for (int off = 32; off > 0; off >>= 1) v += __shfl_xor(v, off, 64);
        if (lane == 0) t_node[node] = v;
    } else if (bid < K1B + RPB) {
        // ---- rowptr: from sorted edge_idx, atomic-free ----
        int e = (bid - K1B) * 256 + tid;
        if (e >= NNZT) return;
        int j = edge_idx[e];
        int jprev = (e == 0) ? -1 : edge_idx[e - 1];
        for (int k = jprev + 1; k <= j; ++k) row_start[k] = e;
        if (e == NNZT - 1)
            for (int k = j + 1; k <= N_EDGES; ++k) row_start[k] = NNZT;
    } else if (bid < K1B + RPB + WCB) {
        // ---- wcvt: Wt[n][k] = (fp16) W[k][n] ----
        int i = (bid - K1B - RPB) * 256 + tid;     // 16384
        int k = i >> 7, n = i & 127;
        wt[(size_t)n * C + k] = (_Float16)W[(size_t)k * C + n];
    } else {
        // ---- bhist: per-bucket totals, wave-private LDS histograms ----
        int bb = bid - K1B - RPB - WCB;            // 0..255
        int w  = tid >> 6;
        for (int b = tid; b < 4 * NB; b += 256) (&cnt4[0][0])[b] = 0;
        __syncthreads();
        const int per = (NNZT + 255) / 256;        // 6250
        int e0 = bb * per;
        int e1 = e0 + per; if (e1 > NNZT) e1 = NNZT;
        for (int e = e0 + tid; e < e1; e += 256)
            atomicAdd(&cnt4[w][node_idx[e] >> 8], 1);
        __syncthreads();
        for (int b = tid; b < NB; b += 256) {
            int cc = cnt4[0][b] + cnt4[1][b] + cnt4[2][b] + cnt4[3][b];
            if (cc) atomicAdd(&btot[b], cc);
        }
    }
}

// K2: segment sum -> m01h row (fp16) + s_edge dot, via row_start.
// ONE WAVE PER ROW: 4 edge-slots x 16 lanes x half8, 4-wide MLP unroll.
// No NT hints (round-2: NT on shared streams poisons later kernels' L2 reuse).
__global__ __launch_bounds__(256) void k2_edge_msg(
    const half8* __restrict__ x0h,
    const int*   __restrict__ node_idx,
    const int*   __restrict__ row_start,
    const float* __restrict__ values,
    const float* __restrict__ att,
    _Float16* __restrict__ m01h,
    float* __restrict__ s_edge)
{
    int wave = threadIdx.x >> 6;
    int lane = threadIdx.x & 63;
    int j    = blockIdx.x * 4 + wave;          // 100000 % 4 == 0
    int sub  = lane >> 4;                      // 0..3 edge slot
    int ln   = lane & 15;                      // half8 chunk of the row
    int start = row_start[j];
    int end   = row_start[j + 1];

    h2 hacc[4];
    #pragma unroll
    for (int q = 0; q < 4; ++q) hacc[q] = (h2){(_Float16)0.f, (_Float16)0.f};

    int e = start + sub;
    for (; e + 12 < end; e += 16) {
        int n0 = node_idx[e];
        int n1 = node_idx[e + 4];
        int n2 = node_idx[e + 8];
        int n3 = node_idx[e + 12];
        float f0 = values[e];
        float f1 = values[e + 4];
        float f2 = values[e + 8];
        float f3 = values[e + 12];
        half8 A  = x0h[(size_t)n0 * 16 + ln];
        half8 B  = x0h[(size_t)n1 * 16 + ln];
        half8 Cg = x0h[(size_t)n2 * 16 + ln];
        half8 D  = x0h[(size_t)n3 * 16 + ln];
        _Float16 v0 = (_Float16)f0, v1 = (_Float16)f1;
        _Float16 v2 = (_Float16)f2, v3 = (_Float16)f3;
        h2 v0p = {v0, v0}, v1p = {v1, v1}, v2p = {v2, v2}, v3p = {v3, v3};
        const h2* a2 = reinterpret_cast<const h2*>(&A);
        const h2* b2 = reinterpret_cast<const h2*>(&B);
        const h2* c2 = reinterpret_cast<const h2*>(&Cg);
        const h2* d2 = reinterpret_cast<const h2*>(&D);
        #pragma unroll
        for (int q = 0; q < 4; ++q)
            hacc[q] = a2[q] * v0p
                    + (b2[q] * v1p + (c2[q] * v2p + (d2[q] * v3p + hacc[q])));
    }
    for (; e + 4 < end; e += 8) {
        int n0 = node_idx[e];
        int n1 = node_idx[e + 4];
        _Float16 v0 = (_Float16)values[e];
        _Float16 v1 = (_Float16)values[e + 4];
        h2 v0p = {v0, v0}, v1p = {v1, v1};
        half8 A = x0h[(size_t)n0 * 16 + ln];
        half8 B = x0h[(size_t)n1 * 16 + ln];
        const h2* a2 = reinterpret_cast<const h2*>(&A);
        const h2* b2 = reinterpret_cast<const h2*>(&B);
        #pragma unroll
        for (int q = 0; q < 4; ++q)
            hacc[q] = a2[q] * v0p + (b2[q] * v1p + hacc[q]);
    }
    if (e < end) {
        int n0 = node_idx[e];
        _Float16 v0 = (_Float16)values[e];
        h2 v0p = {v0, v0};
        half8 A = x0h[(size_t)n0 * 16 + ln];
        const h2* a2 = reinterpret_cast<const h2*>(&A);
        #pragma unroll
        for (int q = 0; q < 4; ++q) hacc[q] = a2[q] * v0p + hacc[q];
    }

    float f[8];
    #pragma unroll
    for (int q = 0; q < 4; ++q) {
        f[2 * q]     = (float)hacc[q][0];
        f[2 * q + 1] = (float)hacc[q][1];
    }
    #pragma unroll
    for (int q = 0; q < 8; ++q) {
        f[q] += __shfl_xor(f[q], 16, 64);
        f[q] += __shfl_xor(f[q], 32, 64);
    }
    if (lane < 16) {
        half8 hv;
        #pragma unroll
        for (int q = 0; q < 8; ++q) hv[q] = (_Float16)f[q];
        reinterpret_cast<half8*>(m01h + (size_t)j * C)[ln] = hv;
    }
    f32x4 a0 = *reinterpret_cast<const f32x4*>(att + ln * 8);
    f32x4 a1 = *reinterpret_cast<const f32x4*>(att + ln * 8 + 4);
    float p = f[0] * a0[0] + f[1] * a0[1] + f[2] * a0[2] + f[3] * a0[3]
            + f[4] * a1[0] + f[5] * a1[1] + f[6] * a1[2] + f[7] * a1[3];
    #pragma unroll
    for (int off = 8; off > 0; off >>= 1) p += __shfl_xor(p, off, 64);
    if (lane == 0) s_edge[j] = p;
}

// BS: exclusive scan of 391 bucket totals -> bbase[0..NB], bcur init.
__global__ __launch_bounds__(512) void k_bscan(
    const int* __restrict__ btot, int* __restrict__ bbase, int* __restrict__ bcur)
{
    __shared__ int s[512];
    int tid = threadIdx.x;
    int v = (tid < NB) ? btot[tid] : 0;
    s[tid] = v;
    __syncthreads();
    for (int off = 1; off < 512; off <<= 1) {
        int t = (tid >= off) ? s[tid - off] : 0;
        __syncthreads();
        s[tid] += t;
        __syncthreads();
    }
    if (tid < NB) { bbase[tid] = s[tid] - v; bcur[tid] = s[tid] - v; }
    if (tid == NB - 1) bbase[NB] = s[tid];
}

// PART: LDS counting-sort partition (temporal-density writes; verified
// round 4: write amplification ~1x). Record: {(n&255)<<17 | j, coef}.
__global__ __launch_bounds__(512) void k_part(
    const int*   __restrict__ node_idx,
    const int*   __restrict__ edge_idx,
    const float* __restrict__ values,
    const float* __restrict__ s_edge,
    const float* __restrict__ t_node,
    int*  __restrict__ bcur,
    int2* __restrict__ rec)
{
    __shared__ int hist[NB];
    __shared__ int lbase[NB];
    __shared__ int gb[NB];
    __shared__ int cur[NB];
    __shared__ int2 lrec[CHUNK];                  // 32 KB
    __shared__ unsigned short lbid[CHUNK];        // 8 KB
    int tid = threadIdx.x;
    int e0 = blockIdx.x * CHUNK;
    int m = NNZT - e0; if (m > CHUNK) m = CHUNK;

    for (int b = tid; b < NB; b += 512) hist[b] = 0;
    __syncthreads();
    for (int i = tid; i < m; i += 512)
        atomicAdd(&hist[node_idx[e0 + i] >> 8], 1);
    __syncthreads();
    int c = (tid < NB) ? hist[tid] : 0;
    for (int off = 1; off < NB; off <<= 1) {
        int t = 0;
        if (tid < NB && tid >= off) t = hist[tid - off];
        __syncthreads();
        if (tid < NB) hist[tid] += t;
        __syncthreads();
    }
    if (tid < NB) {
        int excl = hist[tid] - c;
        lbase[tid] = excl;
        cur[tid]   = excl;
        gb[tid]    = c ? atomicAdd(&bcur[tid], c) : 0;
    }
    __syncthreads();
    for (int i = tid; i < m; i += 512) {
        int e = e0 + i;
        int n = node_idx[e];
        int b = n >> 8;
        int j = edge_idx[e];
        float v = values[e];
        float s = s_edge[j] + t_node[n];
        float coef = (s > 0.f ? s : expm1f(s)) * v;
        int slot = atomicAdd(&cur[b], 1);
        lrec[slot] = make_int2(((n & 255) << 17) | j, __float_as_int(coef));
        lbid[slot] = (unsigned short)b;
    }
    __syncthreads();
    for (int s = tid; s < m; s += 512) {
        int b = lbid[s];
        rec[gb[b] + (s - lbase[b])] = lrec[s];
    }
}

// BSORT: one block per bucket. ONE sequential read of the slab into LDS,
// node-sort via 256-counter hist+scan+ord, ONE dense sequential write of the
// sorted slab (jc) + per-node base/count.
__global__ __launch_bounds__(512) void k_bsort(
    const int2* __restrict__ rec,
    const int*  __restrict__ bbase,
    int2* __restrict__ jc,
    int*  __restrict__ base,
    int*  __restrict__ count)
{
    __shared__ int cnt[256], bl[256], cur[256];
    __shared__ int2 lrec[SCAP];                // 40 KB
    __shared__ unsigned short ord[SCAP];       // 10 KB
    int b = blockIdx.x, tid = threadIdx.x;
    int lo = bbase[b], hi = bbase[b + 1];
    int m = hi - lo;
    bool ovf = (m > SCAP);   // never for this data (mean 4092, cap = +16 sigma)

    if (tid < 256) cnt[tid] = 0;
    __syncthreads();
    for (int i = tid; i < m; i += 512) {
        int2 r = rec[lo + i];
        if (i < SCAP) lrec[i] = r;
        atomicAdd(&cnt[((unsigned)r.x) >> 17], 1);
    }
    __syncthreads();
    if (tid < 256) bl[tid] = cnt[tid];
    __syncthreads();
    for (int off = 1; off < 256; off <<= 1) {
        int t = 0;
        if (tid < 256 && tid >= off) t = bl[tid - off];
        __syncthreads();
        if (tid < 256) bl[tid] += t;
        __syncthreads();
    }
    if (tid < 256) {
        int excl = bl[tid] - cnt[tid];
        cur[tid] = excl;
        int nn = (b << 8) + tid;
        if (nn < N_NODES) { base[nn] = lo + excl; count[nn] = cnt[tid]; }
    }
    __syncthreads();
    if (!ovf) {
        for (int i = tid; i < m; i += 512) {
            int local = ((unsigned)lrec[i].x) >> 17;
            int p = atomicAdd(&cur[local], 1);
            ord[p] = (unsigned short)i;
        }
        __syncthreads();
        for (int s = tid; s < m; s += 512)
            jc[lo + s] = lrec[ord[s]];
    } else {
        // correct-but-slow fallback: scattered (within-slab) direct writes
        for (int i = tid; i < m; i += 512) {
            int2 r = rec[lo + i];
            int local = ((unsigned)r.x) >> 17;
            int p = atomicAdd(&cur[local], 1);
            jc[lo + p] = r;
        }
    }
}

// K3M: fused gather + output GEMM — EXACT round-6 structure (measured 88.8us;
// rounds 7/8 showed both finer (2/wave) and coarser barrier-free (16/wave)
// variants are worse). 256 thr / 4 waves, wave gathers 4 nodes, one barrier,
// then 16x128 @ 128x128 MFMA with 2 col-tiles per wave.
__global__ __launch_bounds__(256) void k3m(
    const int2*  __restrict__ jc,
    const int*   __restrict__ base,
    const int*   __restrict__ count,
    const half8* __restrict__ m01h,
    const _Float16* __restrict__ wt,   // wt[n*C+k] = W[k][n]
    float* __restrict__ out)
{
    __shared__ _Float16 yt[16][136];   // row stride 272B: 16B-aligned, bank-spread
    int tid  = threadIdx.x;
    int wave = tid >> 6, lane = tid & 63, sub = lane >> 4, ln = lane & 15;
    int nb = blockIdx.x * 16;          // 100000 = 6250*16 exactly

    #pragma unroll
    for (int r = 0; r < 4; ++r) {
        int n  = nb + wave * 4 + r;
        int b  = base[n];
        int cc = count[n];
        float facc[8];
        #pragma unroll
        for (int q = 0; q < 8; ++q) facc[q] = 0.f;
        int i = sub;
        for (; i + 12 < cc; i += 16) {            // 4-wide MLP
            int2 r0 = jc[b + i];
            int2 r1 = jc[b + i + 4];
            int2 r2 = jc[b + i + 8];
            int2 r3 = jc[b + i + 12];
            half8 a0 = m01h[(size_t)(r0.x & 0x1FFFF) * 16 + ln];
            half8 a1 = m01h[(size_t)(r1.x & 0x1FFFF) * 16 + ln];
            half8 a2 = m01h[(size_t)(r2.x & 0x1FFFF) * 16 + ln];
            half8 a3 = m01h[(size_t)(r3.x & 0x1FFFF) * 16 + ln];
            float c0 = __int_as_float(r0.y);
            float c1 = __int_as_float(r1.y);
            float c2 = __int_as_float(r2.y);
            float c3 = __int_as_float(r3.y);
            #pragma unroll
            for (int q = 0; q < 8; ++q)
                facc[q] += c0 * (float)a0[q] + c1 * (float)a1[q]
                         + c2 * (float)a2[q] + c3 * (float)a3[q];
        }
        for (; i + 4 < cc; i += 8) {              // 2-wide tail
            int2 r0 = jc[b + i];
            int2 r1 = jc[b + i + 4];
            half8 a0 = m01h[(size_t)(r0.x & 0x1FFFF) * 16 + ln];
            half8 a1 = m01h[(size_t)(r1.x & 0x1FFFF) * 16 + ln];
            float c0 = __int_as_float(r0.y);
            float c1 = __int_as_float(r1.y);
            #pragma unroll
            for (int q = 0; q < 8; ++q)
                facc[q] += c0 * (float)a0[q] + c1 * (float)a1[q];
        }
        if (i < cc) {                             // 1-wide tail
            int2 r0 = jc[b + i];
            half8 a0 = m01h[(size_t)(r0.x & 0x1FFFF) * 16 + ln];
            float c0 = __int_as_float(r0.y);
            #pragma unroll
            for (int q = 0; q < 8; ++q) facc[q] += c0 * (float)a0[q];
        }
        #pragma unroll
        for (int q = 0; q < 8; ++q) {
            facc[q] += __shfl_xor(facc[q], 16, 64);
            facc[q] += __shfl_xor(facc[q], 32, 64);
        }
        if (lane < 16) {
            half8 hv;
            #pragma unroll
            for (int q = 0; q < 8; ++q) hv[q] = (_Float16)facc[q];
            *reinterpret_cast<half8*>(&yt[wave * 4 + r][ln * 8]) = hv;
        }
    }
    __syncthreads();

    // Phase 2: out tile = yt (16x128) @ W (128x128), verified k4 layout.
    int m    = lane & 15;
    int quad = lane >> 4;
    half8 a[4];
    #pragma unroll
    for (int kc = 0; kc < 4; ++kc)
        a[kc] = *reinterpret_cast<const half8*>(&yt[m][quad * 8 + kc * 32]);
    #pragma unroll
    for (int t = 0; t < 2; ++t) {
        int ct = wave * 2 + t;                    // waves cover col-tiles 0..7
        const _Float16* wrow = wt + (size_t)(ct * 16 + m) * C + quad * 8;
        f32x4 acc = {0.f, 0.f, 0.f, 0.f};
        #pragma unroll
        for (int kc = 0; kc < 4; ++kc) {
            half8 bfr = *reinterpret_cast<const half8*>(wrow + kc * 32);
            acc = __builtin_amdgcn_mfma_f32_16x16x32_f16(a[kc], bfr, acc, 0, 0, 0);
        }
        int orow = nb + quad * 4;
        int ocol = ct * 16 + m;
        #pragma unroll
        for (int r = 0; r < 4; ++r)
            out[(size_t)(orow + r) * C + ocol] = acc[r];
    }
}

extern "C" void kernel_launch(void* const* d_in, const int* in_sizes, int n_in,
                              void* d_out, int out_size, void* d_ws, size_t ws_size,
                              hipStream_t stream)
{
    const float* x0       = (const float*)d_in[0];
    const int*   node_idx = (const int*)  d_in[1];
    const int*   edge_idx = (const int*)  d_in[2];
    const float* values   = (const float*)d_in[3];
    const float* W        = (const float*)d_in[4];
    const float* att      = (const float*)d_in[5];
    float* out = (float*)d_out;

    // d_out: [x0h 25.6MB][spare]. x0h dead after k2 -> rec (12.8MB) overlays it;
    // rec dead after k_bsort. k3m writes out (51.2MB = all of d_out) last.
    // m01h lives in ws (must stay live while k3m writes out).
    _Float16* x0h_s = (_Float16*)d_out;
    int2* rec = (int2*)d_out;                                  // 12.8 MB over x0h

    char*  p   = (char*)d_ws;
    _Float16* m01h_s = (_Float16*)p; p += (size_t)N_EDGES * C * sizeof(_Float16); // 25.6 MB
    int2*  jc       = (int2*)p;   p += (size_t)NNZT * sizeof(int2);               // 12.8 MB
    float* t_node   = (float*)p;  p += N_NODES * sizeof(float);
    float* s_edge   = (float*)p;  p += N_EDGES * sizeof(float);
    int*   base     = (int*)p;    p += N_NODES * sizeof(int);
    int*   count    = (int*)p;    p += N_NODES * sizeof(int);
    int*   btot     = (int*)p;    p += 512 * sizeof(int);
    int*   bbase    = (int*)p;    p += 512 * sizeof(int);
    int*   bcur     = (int*)p;    p += 512 * sizeof(int);
    int*   row_start= (int*)p;    p += (N_EDGES + 1) * sizeof(int);
    _Float16* wt    = (_Float16*)p; p += (size_t)C * C * sizeof(_Float16);        // 32 KB

    hipMemsetAsync(btot, 0, NB * sizeof(int), stream);

    k_prep <<<K1B + RPB + WCB + BHB, 256, 0, stream>>>(x0, att, node_idx, edge_idx, W,
                                                       t_node, x0h_s, row_start, wt, btot);
    k2_edge_msg<<<N_EDGES / 4, 256, 0, stream>>>((const half8*)x0h_s, node_idx, row_start,
                                                 values, att, m01h_s, s_edge);
    k_bscan<<<1, 512, 0, stream>>>(btot, bbase, bcur);
    k_part <<<(NNZT + CHUNK - 1) / CHUNK, 512, 0, stream>>>(node_idx, edge_idx, values,
                                                            s_edge, t_node, bcur, rec);
    k_bsort<<<NB, 512, 0, stream>>>(rec, bbase, jc, base, count);
    k3m    <<<N_NODES / 16, 256, 0, stream>>>(jc, base, count, (const half8*)m01h_s,
                                              wt, out);
}